// Round 2
// baseline (272.408 us; speedup 1.0000x reference)
//
#include <hip/hip_runtime.h>

// LocallyConnected1d: out[b,o,l] = sum_i sum_k x[b,i,l+k-4] * w[i,o,k,l] + bias[o,l]
// x: [64][64][512] fp32, weight: [64][64][9][512] fp32 (l innermost), bias: [64][512]
//
// R2: occupancy fix. Thread tile 2b x 4l x 1o (was 4b). 262144 threads = 4096
// waves = 16 waves/CU (50% occ) vs 8 before (latency-bound at VALUBusy=21%).
// Block: 256 thr = 64 l-lanes x 4 waves, each wave a 2-batch group -> the 9
// weight float4 loads per i are identical across the block's 4 waves (L1
// broadcast). launch_bounds(256,4) -> VGPR cap 128 (est ~90 used) so the
// 9 w-quads + 24 x-window floats stay live and loads schedule ahead of FMAs.

#define CIN   64
#define COUT  64
#define SEQ   512
#define KS    9
#define BATCH 64

__global__ __launch_bounds__(256, 4)
void lc1d_kernel(const float* __restrict__ x,
                 const float* __restrict__ w,
                 const float* __restrict__ bias,
                 float* __restrict__ out)
{
    const int lane = threadIdx.x & 63;
    const int wvid = threadIdx.x >> 6;            // 0..3
    const int lq   = blockIdx.x * 64 + lane;      // 0..127 quad idx, l0 = 4*lq
    const int l0   = lq * 4;
    const int o    = blockIdx.y;
    const int b0   = blockIdx.z * 8 + wvid * 2;   // 2 batches per thread

    float acc[2][4];
    #pragma unroll
    for (int b = 0; b < 2; ++b)
        #pragma unroll
        for (int j = 0; j < 4; ++j) acc[b][j] = 0.f;

    const bool left_edge  = (lq == 0);    // x[-4..-1]   -> pad zeros
    const bool right_edge = (lq == 127);  // x[512..515] -> pad zeros

    const float* wp0 = w + ((size_t)o * KS) * SEQ + l0;   // + i*COUT*KS*SEQ per i
    const float* xp0 = x + (size_t)b0 * CIN * SEQ + l0;   // + i*SEQ per i

    for (int i = 0; i < CIN; ++i) {
        // 9 weight quads w[i,o,k,l0..l0+3] — identical across the 4 waves.
        float4 wv[KS];
        const float* wp = wp0 + (size_t)i * (COUT * KS * SEQ);
        #pragma unroll
        for (int k = 0; k < KS; ++k)
            wv[k] = *(const float4*)(wp + k * SEQ);

        #pragma unroll
        for (int b = 0; b < 2; ++b) {
            const float* xp = xp0 + (size_t)(b * CIN + i) * SEQ;
            float4 xa = left_edge  ? make_float4(0.f,0.f,0.f,0.f)
                                   : *(const float4*)(xp - 4);
            float4 xb = *(const float4*)(xp);
            float4 xc = right_edge ? make_float4(0.f,0.f,0.f,0.f)
                                   : *(const float4*)(xp + 4);
            float xwin[12] = {xa.x,xa.y,xa.z,xa.w,
                              xb.x,xb.y,xb.z,xb.w,
                              xc.x,xc.y,xc.z,xc.w};
            #pragma unroll
            for (int k = 0; k < KS; ++k) {
                const float4 wk = wv[k];
                acc[b][0] = fmaf(wk.x, xwin[0 + k], acc[b][0]);
                acc[b][1] = fmaf(wk.y, xwin[1 + k], acc[b][1]);
                acc[b][2] = fmaf(wk.z, xwin[2 + k], acc[b][2]);
                acc[b][3] = fmaf(wk.w, xwin[3 + k], acc[b][3]);
            }
        }
    }

    const float4 bv = *(const float4*)(bias + o * SEQ + l0);
    #pragma unroll
    for (int b = 0; b < 2; ++b) {
        float4 r;
        r.x = acc[b][0] + bv.x;
        r.y = acc[b][1] + bv.y;
        r.z = acc[b][2] + bv.z;
        r.w = acc[b][3] + bv.w;
        *(float4*)(out + ((size_t)((b0 + b) * COUT + o)) * SEQ + l0) = r;
    }
}

extern "C" void kernel_launch(void* const* d_in, const int* in_sizes, int n_in,
                              void* d_out, int out_size, void* d_ws, size_t ws_size,
                              hipStream_t stream) {
    const float* x    = (const float*)d_in[0];
    const float* wgt  = (const float*)d_in[1];
    const float* bias = (const float*)d_in[2];
    float* out        = (float*)d_out;

    dim3 grid(2, COUT, BATCH / 8);  // (l halves, o, b-groups of 8)
    dim3 block(256);
    lc1d_kernel<<<grid, block, 0, stream>>>(x, wgt, bias, out);
}

// Round 3
// 173.759 us; speedup vs baseline: 1.5677x; 1.5677x over previous
//
#include <hip/hip_runtime.h>

// LocallyConnected1d via bf16 MFMA: out[b,o,l] = sum_{i,k} x[b,i,l+k-4]*w[i,o,k,l] + bias[o,l]
// = 512 per-l GEMMs (M=b, N=o, K=(k-major: kk=k*64+i)).
// k-major K-order makes the A-operand RAW x: A_{l,k}[b][i] = x[b,i,(l-4)+k], so one
// LDS x-window Xs[40][16 b][64 i] staged ONCE per block feeds every K-step via
// ds_read_b128 (i-contiguous per lane). Weights stream in 18 chunks (k 0..8 x i-half),
// register-prefetched one chunk ahead, LDS single-buffered.
// Block = 32 l x 16 o x 16 b; grid (64 = lt*4+os, 4 = bsplit) = 256 blocks = 1/CU.
// 32 l * 4 B = exactly one 128B line per weight row -> line-exact read-once weights;
// id%8 is bsplit-invariant -> b-siblings share w lines in the same XCD L2.
// Strides: Xs i-stride 72 (144 B) and Bs i-stride 40 (80 B) are odd multiples of 16 B
// -> conflict-free ds_read_b128 at 16B-block granularity.

#define CIN   64
#define COUT  64
#define SEQ   512
#define KS    9
#define PADL  4
#define LT    32
#define OT    16
#define BT    16
#define LWIN  40          // LT + 2*PADL
#define XSTR  72          // Xs i-stride (bf16 units)
#define BSTR  40          // Bs i-stride (bf16 units)
#define NCHUNK 18         // 9 k * 2 i-halves
#define XS_ELEMS (LWIN*BT*XSTR)            // 46080
#define BS_ELEMS (LT*OT*BSTR)              // 20480
#define LDS_BYTES ((XS_ELEMS + BS_ELEMS)*2) // 133120 B (needs dynamic LDS opt-in)

typedef __attribute__((ext_vector_type(8))) short bf16x8;
typedef __attribute__((ext_vector_type(4))) float f32x4;

__device__ __forceinline__ ushort f2bf(float f) {
    return (ushort)((__float_as_uint(f) + 0x8000u) >> 16);  // round-half-up to bf16
}

__global__ __launch_bounds__(256, 1)
void lc1d_mfma(const float* __restrict__ x, const float* __restrict__ w,
               const float* __restrict__ bias, float* __restrict__ out)
{
    extern __shared__ ushort lds[];
    ushort* Xs = lds;              // [lw 0..39][b 0..15][i 0..63] stride XSTR
    ushort* Bs = lds + XS_ELEMS;   // [lrel 0..31][o 0..15][i 0..31] stride BSTR

    const int tid  = threadIdx.x;
    const int lane = tid & 63;
    const int wv   = tid >> 6;          // wave 0..3 <-> lrel group of 8
    const int lt = blockIdx.x >> 2;     // 0..15 l-tile
    const int os = blockIdx.x & 3;      // o-split
    const int bs = blockIdx.y;          // b-split
    const int l0 = lt * LT;
    const int o0 = os * OT;
    const int b0 = bs * BT;

    const int o16 = tid & 15;           // weight-staging o lane
    const int ip  = tid >> 4;           // 0..15 i-pair

    // ---- prefetch chunk 0 weights into registers ----
    // chunk c: k = c>>1, ih = c&1; thread loads rows i = ih*32 + ip*2 + {0,1},
    // each row = 8 consecutive float4 = the full 128B line w[i, o0+o16, k, l0..l0+31].
    float4 pf[16];
    const float* wbase = w + (size_t)(o0 + o16) * (KS*SEQ) + l0;
    {
        const float* p0 = wbase + (size_t)(ip*2) * (COUT*KS*SEQ);
        const float* p1 = p0 + (COUT*KS*SEQ);
        #pragma unroll
        for (int q = 0; q < 8; ++q) { pf[q] = ((const float4*)p0)[q]; pf[8+q] = ((const float4*)p1)[q]; }
    }

    // ---- stage Xs once: Xs[lw][b][i] = x[b0+b, i, l0-4+lw] (0 outside [0,512)) ----
    #pragma unroll
    for (int rr = 0; rr < 4; ++rr) {
        int row = tid + rr*256;             // 1024 rows = 16 b x 64 i
        int b = row >> 6, i = row & 63;
        const float* src = x + (size_t)((b0 + b)*CIN + i) * SEQ + (l0 - PADL);
        ushort* dst = Xs + b*XSTR + i;
        #pragma unroll
        for (int q = 0; q < 10; ++q) {      // lw = q*4..q*4+3
            float4 v;
            if ((lt == 0 && q == 0) || (lt == 15 && q == 9)) v = make_float4(0.f,0.f,0.f,0.f);
            else v = *(const float4*)(src + q*4);
            dst[(q*4+0)*(BT*XSTR)] = f2bf(v.x);
            dst[(q*4+1)*(BT*XSTR)] = f2bf(v.y);
            dst[(q*4+2)*(BT*XSTR)] = f2bf(v.z);
            dst[(q*4+3)*(BT*XSTR)] = f2bf(v.w);
        }
    }

    f32x4 acc[8];
    #pragma unroll
    for (int j = 0; j < 8; ++j) acc[j] = (f32x4)0.0f;

    __syncthreads();   // Xs ready (chunk-0 loads still draining is fine)

    ushort* bs_wbase = Bs + o16*BSTR + ip*2;                 // + lrel*(OT*BSTR)
    const int aoff = (lane & 15)*XSTR + (lane >> 4)*8;       // b-lane + k-group
    const int boff = (lane & 15)*BSTR + (lane >> 4)*8;       // o-lane + k-group

    for (int c = 0; c < NCHUNK; ++c) {
        // ---- write Bs[lrel][o][i-local] from pf (pack i-pair -> one b32 write) ----
        #pragma unroll
        for (int q = 0; q < 8; ++q) {
            #pragma unroll
            for (int dl = 0; dl < 4; ++dl) {
                float a0 = (&pf[q].x)[dl];       // i even
                float a1 = (&pf[8+q].x)[dl];     // i odd
                uint u0 = __float_as_uint(a0) + 0x8000u;
                uint u1 = __float_as_uint(a1) + 0x8000u;
                uint pk = __builtin_amdgcn_perm(u1, u0, 0x07060302); // (bf(a1)<<16)|bf(a0)
                *(uint*)(bs_wbase + (q*4+dl)*(OT*BSTR)) = pk;
            }
        }
        __syncthreads();  // Bs ready

        // ---- prefetch next chunk (in flight across the MFMA phase) ----
        if (c < NCHUNK-1) {
            int cn = c + 1;
            int kq = cn >> 1, ihn = cn & 1;
            const float* p0 = wbase + (size_t)(ihn*32 + ip*2) * (COUT*KS*SEQ) + kq*SEQ;
            const float* p1 = p0 + (COUT*KS*SEQ);
            #pragma unroll
            for (int q = 0; q < 8; ++q) { pf[q] = ((const float4*)p0)[q]; pf[8+q] = ((const float4*)p1)[q]; }
        }

        // ---- MFMA: wave wv handles lrel = wv*8 + j ----
        {
            int k = c >> 1, ih = c & 1;
            const ushort* Ab = Xs + (wv*8 + k)*(BT*XSTR) + ih*32 + aoff; // lw = lrel + k
            const ushort* Bb = Bs + (wv*8)*(OT*BSTR) + boff;
            #pragma unroll
            for (int j = 0; j < 8; ++j) {
                bf16x8 Af = *(const bf16x8*)(Ab + j*(BT*XSTR));
                bf16x8 Bf = *(const bf16x8*)(Bb + j*(OT*BSTR));
                acc[j] = __builtin_amdgcn_mfma_f32_16x16x32_bf16(Af, Bf, acc[j], 0, 0, 0);
            }
        }
        __syncthreads();  // all waves done reading Bs before next overwrite
    }

    // ---- epilogue: C row = b (=(lane>>4)*4+reg), col = o (=lane&15) ----
    const int orow = o0 + (lane & 15);
    const int rgrp = lane >> 4;
    #pragma unroll
    for (int j = 0; j < 8; ++j) {
        int l = l0 + wv*8 + j;
        float bv = bias[orow*SEQ + l];
        #pragma unroll
        for (int r = 0; r < 4; ++r) {
            int b = b0 + rgrp*4 + r;
            out[(size_t)(b*COUT + orow)*SEQ + l] = acc[j][r] + bv;
        }
    }
}

extern "C" void kernel_launch(void* const* d_in, const int* in_sizes, int n_in,
                              void* d_out, int out_size, void* d_ws, size_t ws_size,
                              hipStream_t stream) {
    const float* x    = (const float*)d_in[0];
    const float* wgt  = (const float*)d_in[1];
    const float* bias = (const float*)d_in[2];
    float* out        = (float*)d_out;

    hipFuncSetAttribute((const void*)lc1d_mfma,
                        hipFuncAttributeMaxDynamicSharedMemorySize, LDS_BYTES);
    dim3 grid(64, 4);   // x = lt*4 + os (id%8 invariant over bsplit), y = bsplit
    lc1d_mfma<<<grid, 256, LDS_BYTES, stream>>>(x, wgt, bias, out);
}

// Round 4
// 163.102 us; speedup vs baseline: 1.6702x; 1.0653x over previous
//
#include <hip/hip_runtime.h>

// LocallyConnected1d via bf16 MFMA: out[b,o,l] = sum_{i,k} x[b,i,l+k-4]*w[i,o,k,l] + bias[o,l]
// 512 per-l GEMMs (M=b=16, N=o=16, K=(k-major) => A-operand is RAW x window).
//
// R4 changes vs R3 (which was vmem-gather bound: 64 lines/instr weight loads,
// pf->use distance ~1 MFMA phase):
//  * Weight staging remapped: thread=(lq 0..7, oo 0..15, pp 0..1) loads i-pairs
//    at fixed l-quad -> each float4 instr = 8 fully-used 128B lines (was 64).
//  * Prefetch distance 2 (pfA/pfB, 2-chunk unrolled loop): vmcnt wait covers a
//    full chunk of LDS+MFMA work.
//  * Bs geometry: o-stride 42 ush, l-stride 674 ush (odd word counts) -> the
//    transposing b32 pair-writes are <=2-way (free). B-frag read = 4x dword
//    (ds_read2_b32, ~3-way) instead of b128.
//  * Xs staging coalesced via flat quad index (~8 lines/instr).
// Block = 32 l x 16 o x 16 b; grid (64,4) = 256 blocks = 1/CU (LDS 132 KB).

#define CIN   64
#define COUT  64
#define SEQ   512
#define KS    9
#define LT    32
#define OT    16
#define BT    16
#define LWIN  40
#define XSTR  72                     // Xs b-stride (ush): 64 i + 8 pad (odd 16B-quad count)
#define XLW   (BT*XSTR)              // Xs lw-stride = 1152 ush
#define BOSTR 42                     // Bs o-stride (ush): 32 i + 10 pad (odd word count 21)
#define BLSTR (OT*BOSTR + 2)         // Bs l-stride = 674 ush (word count 337, odd)
#define NCHUNK 18                    // 9 k-taps x 2 i-halves
#define WSTRIDE (COUT*KS*SEQ)        // weight i-stride in floats
#define XS_ELEMS (LWIN*XLW)          // 46080 ush
#define BS_ELEMS (LT*BLSTR)          // 21568 ush
#define LDS_BYTES ((XS_ELEMS + BS_ELEMS)*2)   // 135296 B

typedef __attribute__((ext_vector_type(8))) short bf16x8;
typedef __attribute__((ext_vector_type(4))) float f32x4;

__device__ __forceinline__ ushort f2bf(float f) {
    return (ushort)((__float_as_uint(f) + 0x8000u) >> 16);
}
__device__ __forceinline__ uint pack2bf(float a0, float a1) {
    uint u0 = __float_as_uint(a0) + 0x8000u;   // bf(a0) in bytes 2..3
    uint u1 = __float_as_uint(a1) + 0x8000u;
    return __builtin_amdgcn_perm(u1, u0, 0x07060302);  // (bf(a1)<<16)|bf(a0)
}

__global__ __launch_bounds__(256, 1)
void lc1d_mfma(const float* __restrict__ x, const float* __restrict__ w,
               const float* __restrict__ bias, float* __restrict__ out)
{
    extern __shared__ ushort lds[];
    ushort* Xs = lds;              // [lw 0..39][b 0..15][i 0..63] (stride XSTR)
    ushort* Bs = lds + XS_ELEMS;   // [lrel 0..31][o 0..15][i 0..31] (strides BLSTR/BOSTR)

    const int tid  = threadIdx.x;
    const int lane = tid & 63;
    const int wv   = tid >> 6;
    const int lt  = blockIdx.x >> 2;
    const int os  = blockIdx.x & 3;
    const int bsp = blockIdx.y;
    const int l0 = lt * LT;
    const int o0 = os * OT;
    const int b0 = bsp * BT;

    // ---- weight-staging lane mapping: coalesced along l ----
    const int lq = tid & 7;            // l-quad 0..7
    const int oo = (tid >> 3) & 15;    // o
    const int pp = tid >> 7;           // i-pair half 0..1

    const float* wbase = w + ((size_t)(o0 + oo) * KS) * SEQ + l0 + lq * 4;

    float4 pfA[16], pfB[16];

    // chunk c: kq = c>>1 (kernel tap), ih = c&1 (i-half). Thread loads 8 i-pairs
    // m = pp*8+p : rows i = ih*32 + 2m, 2m+1, one float4 at its l-quad.
    // Per instruction: 8 lq-lanes x 16B = one full 128B line, x 8 oo = 8 lines.
    #define LOAD_CHUNK(pf, c) {                                                  \
        const int kq_ = (c) >> 1, ih_ = (c) & 1;                                 \
        const float* p_ = wbase + (size_t)kq_ * SEQ                              \
                          + (size_t)(ih_*32 + pp*16) * WSTRIDE;                  \
        _Pragma("unroll")                                                        \
        for (int p8 = 0; p8 < 8; ++p8) {                                         \
            pf[2*p8]   = *(const float4*)(p_ + (size_t)(2*p8  ) * WSTRIDE);      \
            pf[2*p8+1] = *(const float4*)(p_ + (size_t)(2*p8+1) * WSTRIDE);      \
        }                                                                        \
    }

    // transpose+convert into Bs: b32 write of i-pair (2m,2m+1) at [lrel][oo].
    // word = lrel*337 + oo*21 + m -> banks 4*lq + 21*oo + c : max 2-way (free).
    #define WRITE_BS(pf) {                                                       \
        _Pragma("unroll")                                                        \
        for (int p8 = 0; p8 < 8; ++p8) {                                         \
            const int m_ = pp*8 + p8;                                            \
            ushort* dst_ = Bs + oo*BOSTR + 2*m_ + lq*4*BLSTR;                    \
            _Pragma("unroll")                                                    \
            for (int dl = 0; dl < 4; ++dl) {                                     \
                uint pk_ = pack2bf((&pf[2*p8].x)[dl], (&pf[2*p8+1].x)[dl]);      \
                *(uint*)(dst_ + dl*BLSTR) = pk_;                                 \
            }                                                                    \
        }                                                                        \
    }

    // ---- issue chunk 0/1 weight prefetch first (oldest in vmcnt queue) ----
    LOAD_CHUNK(pfA, 0)
    LOAD_CHUNK(pfB, 1)

    // ---- stage Xs (once): coalesced flat-quad iteration ----
    // 1024 rows (16b x 64i) x 10 quads; flat = tid + 256*it.
    #pragma unroll
    for (int it = 0; it < 40; ++it) {
        int flat = tid + 256*it;
        int row = flat / 10;
        int q   = flat - row*10;       // l-window quad 0..9
        int b = row >> 6, i = row & 63;
        const float* src = x + ((size_t)((b0 + b)*CIN + i))*SEQ + (l0 - 4) + q*4;
        float4 v = make_float4(0.f, 0.f, 0.f, 0.f);
        if (!((lt == 0 && q == 0) || (lt == 15 && q == 9)))
            v = *(const float4*)src;
        ushort* dst = Xs + (q*4)*XLW + b*XSTR + i;
        dst[0*XLW] = f2bf(v.x);
        dst[1*XLW] = f2bf(v.y);
        dst[2*XLW] = f2bf(v.z);
        dst[3*XLW] = f2bf(v.w);
    }

    f32x4 acc[8];
    #pragma unroll
    for (int j = 0; j < 8; ++j) acc[j] = (f32x4)0.0f;

    const int aoff = (lane & 15)*XSTR + (lane >> 4)*8;   // b-lane + k-group
    const int boff = (lane & 15)*BOSTR + (lane >> 4)*8;  // o-lane + k-group

    __syncthreads();   // Xs ready

    // wave wv owns lrel = wv*8 + j. A from Xs (b128), B from Bs (4x dword).
    #define DO_MFMA(c) {                                                         \
        const int kq_ = (c) >> 1, ih_ = (c) & 1;                                 \
        const ushort* Ab_ = Xs + (wv*8 + kq_)*XLW + ih_*32 + aoff;               \
        const ushort* Bb_ = Bs + (wv*8)*BLSTR + boff;                            \
        _Pragma("unroll")                                                        \
        for (int j = 0; j < 8; ++j) {                                            \
            bf16x8 Af_ = *(const bf16x8*)(Ab_ + j*XLW);                          \
            const uint* bw_ = (const uint*)(Bb_ + j*BLSTR);                      \
            uint4 bu_ = make_uint4(bw_[0], bw_[1], bw_[2], bw_[3]);              \
            bf16x8 Bf_ = __builtin_bit_cast(bf16x8, bu_);                        \
            acc[j] = __builtin_amdgcn_mfma_f32_16x16x32_bf16(Af_, Bf_, acc[j],   \
                                                             0, 0, 0);           \
        }                                                                        \
    }

    for (int cc = 0; cc < NCHUNK; cc += 2) {
        WRITE_BS(pfA)
        __syncthreads();                      // Bs(cc) ready
        if (cc + 2 < NCHUNK) LOAD_CHUNK(pfA, cc + 2)
        DO_MFMA(cc)
        __syncthreads();                      // all waves done with Bs(cc)

        WRITE_BS(pfB)
        __syncthreads();                      // Bs(cc+1) ready
        if (cc + 3 < NCHUNK) LOAD_CHUNK(pfB, cc + 3)
        DO_MFMA(cc + 1)
        __syncthreads();
    }

    // ---- epilogue: C col = o = lane&15, row = b = (lane>>4)*4 + reg ----
    const int orow = o0 + (lane & 15);
    const int rgrp = lane >> 4;
    #pragma unroll
    for (int j = 0; j < 8; ++j) {
        int l = l0 + wv*8 + j;
        float bv = bias[orow*SEQ + l];
        #pragma unroll
        for (int r = 0; r < 4; ++r) {
            int b = b0 + rgrp*4 + r;
            out[(size_t)(b*COUT + orow)*SEQ + l] = acc[j][r] + bv;
        }
    }
}

extern "C" void kernel_launch(void* const* d_in, const int* in_sizes, int n_in,
                              void* d_out, int out_size, void* d_ws, size_t ws_size,
                              hipStream_t stream) {
    const float* x    = (const float*)d_in[0];
    const float* wgt  = (const float*)d_in[1];
    const float* bias = (const float*)d_in[2];
    float* out        = (float*)d_out;

    hipFuncSetAttribute((const void*)lc1d_mfma,
                        hipFuncAttributeMaxDynamicSharedMemorySize, LDS_BYTES);
    dim3 grid(64, 4);   // x = lt*4 + os, y = b-split (id%8 invariant over bsplit)
    lc1d_mfma<<<grid, 256, LDS_BYTES, stream>>>(x, wgt, bias, out);
}

// Round 5
// 162.863 us; speedup vs baseline: 1.6726x; 1.0015x over previous
//
#include <hip/hip_runtime.h>

// LocallyConnected1d via bf16 MFMA: out[b,o,l] = sum_{i,k} x[b,i,l+k-4]*w[i,o,k,l] + bias[o,l]
// 512 per-l GEMMs (M=b=16, N=o=16, K=(k-major) => A-operand is RAW x window).
//
// R5: TLP restructure. R3/R4 ran 1 wave/SIMD (1 block/CU x 4 waves) -> fully
// latency-exposed (VALUBusy 4%, Occ 7%). Now: tile LT 32->16, 512 thr/block
// (8 waves), LDS 135->76.9 KB -> 2 blocks/CU, grid 512 -> 16 waves/CU =
// 4 waves/SIMD. Same chunk pipeline: 18 chunks (9 k-taps x 2 i-halves),
// distance-2 register prefetch (pfA/pfB), odd-stride Bs for the fp32->bf16
// transpose (writes ~3-way max, reads ~2-3-way, both cheap), Xs staged once.

#define CIN   64
#define COUT  64
#define SEQ   512
#define KS    9
#define LT    16
#define OT    16
#define BT    16
#define LWIN  24                     // LT + 2*4 halo
#define XSTR  72                     // Xs b-stride (ush): 64 i + 8 pad (odd 16B-quad count)
#define XLW   (BT*XSTR)              // Xs lw-stride = 1152 ush
#define BOSTR 42                     // Bs o-stride (ush): 32 i + 10 pad (odd word count)
#define BLSTR (OT*BOSTR + 2)         // Bs lrel-stride = 674 ush (odd word count)
#define NCHUNK 18
#define WSTRIDE (COUT*KS*SEQ)        // weight i-stride in floats
#define XS_ELEMS (LWIN*XLW)          // 27648 ush
#define BS_ELEMS (LT*BLSTR)          // 10784 ush
#define LDS_BYTES ((XS_ELEMS + BS_ELEMS)*2)   // 76864 B -> 2 blocks/CU

typedef __attribute__((ext_vector_type(8))) short bf16x8;
typedef __attribute__((ext_vector_type(4))) float f32x4;

__device__ __forceinline__ ushort f2bf(float f) {
    return (ushort)((__float_as_uint(f) + 0x8000u) >> 16);
}
__device__ __forceinline__ uint pack2bf(float a0, float a1) {
    uint u0 = __float_as_uint(a0) + 0x8000u;
    uint u1 = __float_as_uint(a1) + 0x8000u;
    return __builtin_amdgcn_perm(u1, u0, 0x07060302);  // (bf(a1)<<16)|bf(a0)
}

__global__ __launch_bounds__(512, 4)
void lc1d_mfma(const float* __restrict__ x, const float* __restrict__ w,
               const float* __restrict__ bias, float* __restrict__ out)
{
    extern __shared__ ushort lds[];
    ushort* Xs = lds;              // [lw 0..23][b 0..15][i 0..63]
    ushort* Bs = lds + XS_ELEMS;   // [lrel 0..15][o 0..15][i-local 0..31]

    const int tid  = threadIdx.x;
    const int lane = tid & 63;
    const int wv   = tid >> 6;          // 0..7
    const int lt  = blockIdx.x >> 2;    // 0..31
    const int os  = blockIdx.x & 3;
    const int bsp = blockIdx.y;
    const int l0 = lt * LT;
    const int o0 = os * OT;
    const int b0 = bsp * BT;

    // ---- weight-staging lane mapping (coalesced along l, o across lanes) ----
    const int lq = tid & 3;            // l-quad 0..3
    const int oo = (tid >> 2) & 15;    // o
    const int ig = tid >> 6;           // i-group 0..7 (== wave id)

    const float* wbase = w + ((size_t)(o0 + oo) * KS) * SEQ + l0 + lq * 4;

    float4 pfA[4], pfB[4];

    // chunk c: kq=c>>1 (tap), ih=c&1 (i-half). Thread loads i = ih*32+ig*4+q.
    #define LOAD_CHUNK(pf, c) {                                                  \
        const int kq_ = (c) >> 1, ih_ = (c) & 1;                                 \
        const float* p_ = wbase + (size_t)kq_ * SEQ                              \
                          + (size_t)(ih_*32 + ig*4) * WSTRIDE;                   \
        _Pragma("unroll")                                                        \
        for (int q = 0; q < 4; ++q)                                              \
            pf[q] = *(const float4*)(p_ + (size_t)q * WSTRIDE);                  \
    }

    // transpose+convert: pack i-pair (pf[2s],pf[2s+1]) -> b32 at [lrel][oo][ig*4+2s]
    #define WRITE_BS(pf) {                                                       \
        _Pragma("unroll")                                                        \
        for (int s = 0; s < 2; ++s) {                                            \
            _Pragma("unroll")                                                    \
            for (int dl = 0; dl < 4; ++dl) {                                     \
                uint pk_ = pack2bf((&pf[2*s].x)[dl], (&pf[2*s+1].x)[dl]);        \
                *(uint*)(Bs + (lq*4+dl)*BLSTR + oo*BOSTR + ig*4 + 2*s) = pk_;    \
            }                                                                    \
        }                                                                        \
    }

    LOAD_CHUNK(pfA, 0)
    LOAD_CHUNK(pfB, 1)

    // ---- stage Xs once: Xs[lw][b][i] = bf16(x[b0+b, i, l0-4+lw]) ----
    // 1024 rows (16b x 64i) x 6 quads = 6144 float4s; flat = tid + 512*it.
    #pragma unroll
    for (int it = 0; it < 12; ++it) {
        int flat = tid + 512*it;
        int row = flat / 6;
        int q   = flat - row*6;        // l-window quad 0..5
        int b = row >> 6, i = row & 63;
        const float* src = x + ((size_t)((b0 + b)*CIN + i))*SEQ + (l0 - 4) + q*4;
        float4 v = make_float4(0.f, 0.f, 0.f, 0.f);
        if (!((lt == 0 && q == 0) || (lt == 31 && q == 5)))
            v = *(const float4*)src;
        ushort* dst = Xs + (q*4)*XLW + b*XSTR + i;
        dst[0*XLW] = f2bf(v.x);
        dst[1*XLW] = f2bf(v.y);
        dst[2*XLW] = f2bf(v.z);
        dst[3*XLW] = f2bf(v.w);
    }

    f32x4 acc[2];
    acc[0] = (f32x4)0.0f;
    acc[1] = (f32x4)0.0f;

    const int aoff = (lane & 15)*XSTR  + (lane >> 4)*8;  // b-lane + k-group
    const int boff = (lane & 15)*BOSTR + (lane >> 4)*8;  // o-lane + k-group

    __syncthreads();   // Xs ready

    // wave wv owns lrel = wv*2 + {0,1}
    #define DO_MFMA(c) {                                                         \
        const int kq_ = (c) >> 1, ih_ = (c) & 1;                                 \
        _Pragma("unroll")                                                        \
        for (int jr = 0; jr < 2; ++jr) {                                         \
            const int r_ = wv*2 + jr;                                            \
            bf16x8 Af_ = *(const bf16x8*)(Xs + (r_ + kq_)*XLW + ih_*32 + aoff);  \
            const uint* bw_ = (const uint*)(Bs + r_*BLSTR + boff);               \
            uint4 bu_ = make_uint4(bw_[0], bw_[1], bw_[2], bw_[3]);              \
            bf16x8 Bf_ = __builtin_bit_cast(bf16x8, bu_);                        \
            acc[jr] = __builtin_amdgcn_mfma_f32_16x16x32_bf16(Af_, Bf_, acc[jr], \
                                                              0, 0, 0);          \
        }                                                                        \
    }

    for (int cc = 0; cc < NCHUNK; cc += 2) {
        WRITE_BS(pfA)
        __syncthreads();                       // Bs(cc) ready
        if (cc + 2 < NCHUNK) LOAD_CHUNK(pfA, cc + 2)
        DO_MFMA(cc)
        __syncthreads();                       // all waves done with Bs(cc)

        WRITE_BS(pfB)
        __syncthreads();                       // Bs(cc+1) ready
        if (cc + 3 < NCHUNK) LOAD_CHUNK(pfB, cc + 3)
        DO_MFMA(cc + 1)
        __syncthreads();
    }

    // ---- epilogue: C col = o = lane&15, row = b = (lane>>4)*4 + reg ----
    const int orow = o0 + (lane & 15);
    const int rgrp = lane >> 4;
    #pragma unroll
    for (int jr = 0; jr < 2; ++jr) {
        int l = l0 + wv*2 + jr;
        float bv = bias[orow*SEQ + l];
        #pragma unroll
        for (int r = 0; r < 4; ++r) {
            int b = b0 + rgrp*4 + r;
            out[(size_t)(b*COUT + orow)*SEQ + l] = acc[jr][r] + bv;
        }
    }
}

extern "C" void kernel_launch(void* const* d_in, const int* in_sizes, int n_in,
                              void* d_out, int out_size, void* d_ws, size_t ws_size,
                              hipStream_t stream) {
    const float* x    = (const float*)d_in[0];
    const float* wgt  = (const float*)d_in[1];
    const float* bias = (const float*)d_in[2];
    float* out        = (float*)d_out;

    hipFuncSetAttribute((const void*)lc1d_mfma,
                        hipFuncAttributeMaxDynamicSharedMemorySize, LDS_BYTES);
    dim3 grid(128, 4);  // x = lt*4 + os (id%8 invariant over bsplit), y = bsplit
    lc1d_mfma<<<grid, 512, LDS_BYTES, stream>>>(x, wgt, bias, out);
}